// Round 3
// baseline (1781.488 us; speedup 1.0000x reference)
//
#include <hip/hip_runtime.h>
#include <hip/hip_bf16.h>

#define N_NODES 100000
#define N_EDGES 300000
#define IN_DIM 10
#define HID 384
#define OUT_DIM 3
#define T_LAYERS 5
#define BN_EPS 1e-5f

typedef __attribute__((ext_vector_type(8))) short short8;
typedef __attribute__((ext_vector_type(4))) float floatx4;

__device__ __forceinline__ float bf16f(short v) {
  return __uint_as_float(((unsigned)(unsigned short)v) << 16);
}

// ------------------------- CSR build -------------------------

__global__ void count_k(const int* __restrict__ dst, int* __restrict__ cnt, int E) {
  int e = blockIdx.x * blockDim.x + threadIdx.x;
  if (e < E) atomicAdd(&cnt[dst[e]], 1);
}

__global__ void scan_partial_k(const int* __restrict__ cnt, int* __restrict__ bsum, int n) {
  int t = threadIdx.x;
  int i = blockIdx.x * 1024 + t;
  int v = (i < n) ? cnt[i] : 0;
  #pragma unroll
  for (int off = 1; off < 64; off <<= 1) v += __shfl_xor(v, off);
  __shared__ int ws[16];
  if ((t & 63) == 0) ws[t >> 6] = v;
  __syncthreads();
  if (t == 0) {
    int s = 0;
    #pragma unroll
    for (int w = 0; w < 16; ++w) s += ws[w];
    bsum[blockIdx.x] = s;
  }
}

__global__ void scan_small_k(int* __restrict__ bsum, int P) {
  __shared__ int s[1024];
  int t = threadIdx.x;
  int v = (t < P) ? bsum[t] : 0;
  s[t] = v;
  __syncthreads();
  for (int off = 1; off < 1024; off <<= 1) {
    int add = (t >= off) ? s[t - off] : 0;
    __syncthreads();
    s[t] += add;
    __syncthreads();
  }
  if (t < P) bsum[t] = s[t] - v;  // exclusive block-prefix
}

__global__ void scan_final_k(const int* __restrict__ cnt, const int* __restrict__ bsum,
                             int* __restrict__ row_off, int n) {
  int t = threadIdx.x, lane = t & 63, wv = t >> 6;
  int i = blockIdx.x * 1024 + t;
  int v = (i < n) ? cnt[i] : 0;
  int x = v;
  #pragma unroll
  for (int off = 1; off < 64; off <<= 1) {
    int y = __shfl_up(x, off);
    if (lane >= off) x += y;
  }
  __shared__ int ws[16];
  if (lane == 63) ws[wv] = x;
  __syncthreads();
  if (t == 0) {
    int a = 0;
    #pragma unroll
    for (int w = 0; w < 16; ++w) { int tmp = ws[w]; ws[w] = a; a += tmp; }
  }
  __syncthreads();
  int excl = (x - v) + ws[wv] + bsum[blockIdx.x];
  if (i <= n) row_off[i] = excl;
}

__global__ void fill_k(const int* __restrict__ src, const int* __restrict__ dst,
                       const int* __restrict__ row_off, int* __restrict__ cursor,
                       int* __restrict__ csr, int E) {
  int e = blockIdx.x * blockDim.x + threadIdx.x;
  if (e < E) {
    int d = dst[e];
    int pos = atomicAdd(&cursor[d], 1);
    csr[row_off[d] + pos] = src[e];
  }
}

// ------------------------- prepack kernels -------------------------

__global__ void conv_k(const float* __restrict__ src, __hip_bfloat16* __restrict__ dst, int n) {
  int i = blockIdx.x * blockDim.x + threadIdx.x;
  if (i < n) dst[i] = __float2bfloat16(src[i]);
}

// X2[n][64] = { x[n][0..10) , agg10[n][0..10) , 0 pad }
__global__ void pack0_k(const float* __restrict__ x, const float* __restrict__ agg10,
                        __hip_bfloat16* __restrict__ X2, int n) {
  int i = blockIdx.x * blockDim.x + threadIdx.x;
  if (i < n * 64) {
    int node = i >> 6, k = i & 63;
    float v = (k < IN_DIM) ? x[node * IN_DIM + k]
              : (k < 2 * IN_DIM) ? agg10[node * IN_DIM + (k - IN_DIM)] : 0.f;
    X2[i] = __float2bfloat16(v);
  }
}

// W2[o][64] = { W_r0 (pairs x) , W_l0 (pairs agg10) , 0 pad }
__global__ void packw0_k(const float* __restrict__ Wl, const float* __restrict__ Wr,
                         __hip_bfloat16* __restrict__ W2) {
  int i = blockIdx.x * blockDim.x + threadIdx.x;
  if (i < HID * 64) {
    int o = i >> 6, k = i & 63;
    float v = (k < IN_DIM) ? Wr[o * IN_DIM + k]
              : (k < 2 * IN_DIM) ? Wl[o * IN_DIM + (k - IN_DIM)]
              : 0.f;
    W2[i] = __float2bfloat16(v);
  }
}

// ------------------------- aggregation -------------------------

__global__ void agg10_k(const float* __restrict__ x, const int* __restrict__ row_off,
                        const int* __restrict__ csr, float* __restrict__ agg10, int n) {
  int sub = threadIdx.x >> 5;
  int lane = threadIdx.x & 31;
  int node = blockIdx.x * 8 + sub;
  if (node >= n) return;
  int s = row_off[node], e = row_off[node + 1];
  if (lane < IN_DIM) {
    float acc = 0.f;
    for (int j = s; j < e; ++j) acc += x[csr[j] * IN_DIM + lane];
    float c = (float)max(e - s, 1);
    agg10[node * IN_DIM + lane] = acc / c;
  }
}

// F=384 mean aggregation: one wave per node, lanes 0..47 hold 8 bf16 cols each.
__global__ __launch_bounds__(256) void aggv_k(const __hip_bfloat16* __restrict__ h,
                                              const int* __restrict__ row_off,
                                              const int* __restrict__ csr,
                                              __hip_bfloat16* __restrict__ agg, int n) {
  int node = blockIdx.x * 4 + (threadIdx.x >> 6);
  if (node >= n) return;
  int lane = threadIdx.x & 63;
  if (lane >= 48) return;
  int s = row_off[node], e = row_off[node + 1];
  float acc[8] = {0.f, 0.f, 0.f, 0.f, 0.f, 0.f, 0.f, 0.f};
  for (int j = s; j < e; ++j) {
    const uint4 v = *(const uint4*)(h + (size_t)csr[j] * HID + lane * 8);
    uint u0 = v.x, u1 = v.y, u2 = v.z, u3 = v.w;
    acc[0] += __uint_as_float(u0 << 16);
    acc[1] += __uint_as_float(u0 & 0xffff0000u);
    acc[2] += __uint_as_float(u1 << 16);
    acc[3] += __uint_as_float(u1 & 0xffff0000u);
    acc[4] += __uint_as_float(u2 << 16);
    acc[5] += __uint_as_float(u2 & 0xffff0000u);
    acc[6] += __uint_as_float(u3 << 16);
    acc[7] += __uint_as_float(u3 & 0xffff0000u);
  }
  float invc = 1.f / (float)max(e - s, 1);
  uint out[4];
  #pragma unroll
  for (int q = 0; q < 4; ++q) {
    __hip_bfloat16 lo = __float2bfloat16(acc[2 * q] * invc);
    __hip_bfloat16 hi = __float2bfloat16(acc[2 * q + 1] * invc);
    out[q] = (uint)(*(unsigned short*)&lo) | ((uint)(*(unsigned short*)&hi) << 16);
  }
  *(uint4*)(agg + (size_t)node * HID + lane * 8) = make_uint4(out[0], out[1], out[2], out[3]);
}

// ------------------------- MFMA GEMM, fused epilogue -------------------------
// out[i, col] = sum_k A1[i,k]*B1[col,k] (+ A2[i,k]*B2[col,k]) + bias[col]
// r9 structure: BARRIER-FREE K-loop (per-wave independent GEMM workers).
//  * r7/r8 post-mortem: every per-chunk vmcnt(0)+s_barrier is the T4
//    anti-pattern ("phase-with-drain0 == no pipeline"). With only 2 waves/SIMD
//    each chunk exposed the residual L2/L3 latency; both "pipelined" variants
//    regressed vs. the r4 baseline (150->184->191 us, MfmaUtil 16->13->12.5).
//  * Fix: A-fragments are loaded DIRECT global->reg, like B. The A-frag
//    pattern (16 rows x 64 contiguous B per instruction) is exactly as
//    line-coalesced as via LDS; the 4 waves of a block share A lines through
//    L1 (1 miss + 3 hits). NO LDS staging, NO K-loop barriers, NO inline asm.
//    Each wave runs its own 64x96 tile pipeline; the compiler schedules loads
//    vs. MFMA by register dependency (its known-good regime), and wave drift
//    does the latency hiding the lockstep structure prevented.
//  * In-place safety (out == A1/A2): epilogue packs to LDS and __syncthreads()
//    before any global write, so all waves' A-reads complete first.
//  * Spill tripwire: WRITE_SIZE must stay at 75 MB (arch ~130 + 96 acc regs).
// Epilogue: pack bf16 to LDS (stride 392), coalesced dwordx4 out.
template <int KTOT, bool DUAL, int EPI, bool FINAL>
__global__ __launch_bounds__(256, 2) void mfma_gemm_k(
    const __hip_bfloat16* __restrict__ A1, const __hip_bfloat16* __restrict__ B1,
    const __hip_bfloat16* __restrict__ A2, const __hip_bfloat16* __restrict__ B2,
    const float* __restrict__ bias,
    const float* __restrict__ bng, const float* __restrict__ bnb,
    const float* __restrict__ bnm, const float* __restrict__ bnv,
    __hip_bfloat16* __restrict__ out,
    const float* __restrict__ W3, const float* __restrict__ b3,
    float* __restrict__ out3) {
  // LDS used ONLY by the epilogue: norm-reduce scratch, then sO[64][392] pack.
  __shared__ alignas(16) short smem[64 * 392];  // 50176 B

  const int t = threadIdx.x;
  const int lane = t & 63;
  const int wv = t >> 6;
  const int n16 = lane & 15;
  const int quad = lane >> 4;
  const int row0 = blockIdx.x * 64;

  constexpr int KCH = KTOT / 64;
  constexpr int NCH = DUAL ? 2 * KCH : KCH;

  // per-lane A row bases (elements): row rt*16 + n16 of this block's 64 rows
  size_t arow[4];
  #pragma unroll
  for (int rt = 0; rt < 4; ++rt)
    arow[rt] = (size_t)min(row0 + rt * 16 + n16, N_NODES - 1) * KTOT;

  // per-lane B fragment base offsets (elements)
  int boff[6];
  #pragma unroll
  for (int ct = 0; ct < 6; ++ct)
    boff[ct] = (wv * 96 + ct * 16 + n16) * KTOT + quad * 8;

  const int kq = quad * 8;  // k sub-offset within a 32-wide half-chunk

  floatx4 acc[4][6];
  #pragma unroll
  for (int rt = 0; rt < 4; ++rt)
    #pragma unroll
    for (int ct = 0; ct < 6; ++ct) acc[rt][ct] = (floatx4)0.f;

  #pragma unroll 2
  for (int c = 0; c < NCH; ++c) {
    const __hip_bfloat16* Ap;
    const __hip_bfloat16* Bp;
    int kc;
    if (!DUAL || c < KCH) { Ap = A1; Bp = B1; kc = c * 64; }
    else                  { Ap = A2; Bp = B2; kc = (c - KCH) * 64; }

    short8 af[2][4], bf[2][6];
    #pragma unroll
    for (int kh = 0; kh < 2; ++kh) {
      #pragma unroll
      for (int rt = 0; rt < 4; ++rt)
        af[kh][rt] = *(const short8*)(Ap + arow[rt] + kc + kh * 32 + kq);
      #pragma unroll
      for (int ct = 0; ct < 6; ++ct)
        bf[kh][ct] = *(const short8*)(Bp + boff[ct] + kc + kh * 32);
    }
    #pragma unroll
    for (int kh = 0; kh < 2; ++kh)
      #pragma unroll
      for (int rt = 0; rt < 4; ++rt)
        #pragma unroll
        for (int ct = 0; ct < 6; ++ct)
          acc[rt][ct] = __builtin_amdgcn_mfma_f32_16x16x32_bf16(af[kh][rt], bf[kh][ct], acc[rt][ct], 0, 0, 0);
  }

  // ---- epilogue ----
  int gc[6];
  #pragma unroll
  for (int ct = 0; ct < 6; ++ct) {
    gc[ct] = wv * 96 + ct * 16 + n16;
    float bs = bias[gc[ct]];
    #pragma unroll
    for (int rt = 0; rt < 4; ++rt)
      #pragma unroll
      for (int rg = 0; rg < 4; ++rg) acc[rt][ct][rg] += bs;
  }

  if constexpr (EPI == 0) {
    // row L2 norm: 16-lane shfl reduce, then cross-wave via LDS
    float* red = (float*)smem;
    float inv[4][4];
    #pragma unroll
    for (int rt = 0; rt < 4; ++rt)
      #pragma unroll
      for (int rg = 0; rg < 4; ++rg) {
        float s = 0.f;
        #pragma unroll
        for (int ct = 0; ct < 6; ++ct) s += acc[rt][ct][rg] * acc[rt][ct][rg];
        #pragma unroll
        for (int off = 1; off < 16; off <<= 1) s += __shfl_xor(s, off);
        if (n16 == 0) red[wv * 64 + rt * 16 + quad * 4 + rg] = s;
      }
    __syncthreads();
    #pragma unroll
    for (int rt = 0; rt < 4; ++rt)
      #pragma unroll
      for (int rg = 0; rg < 4; ++rg) {
        int rl = rt * 16 + quad * 4 + rg;
        float ss = red[rl] + red[64 + rl] + red[128 + rl] + red[192 + rl];
        inv[rt][rg] = 1.f / fmaxf(sqrtf(ss), 1e-12f);
      }
    #pragma unroll
    for (int rt = 0; rt < 4; ++rt)
      #pragma unroll
      for (int ct = 0; ct < 6; ++ct)
        #pragma unroll
        for (int rg = 0; rg < 4; ++rg) acc[rt][ct][rg] *= inv[rt][rg];
    __syncthreads();  // red reads done before smem reused as sO
  }

  // BN + activation, pack bf16 into LDS (row stride 392 shorts)
  constexpr int OS = 392;
  short* sO = smem;
  #pragma unroll
  for (int ct = 0; ct < 6; ++ct) {
    int col = gc[ct];
    float sc = bng[col] * rsqrtf(bnv[col] + BN_EPS);
    float sh = bnb[col] - bnm[col] * sc;
    #pragma unroll
    for (int rt = 0; rt < 4; ++rt)
      #pragma unroll
      for (int rg = 0; rg < 4; ++rg) {
        float xv = acc[rt][ct][rg] * sc + sh;
        if constexpr (EPI == 0)
          xv = xv > 0.f ? xv : expm1f(xv);
        else
          xv = fmaxf(xv, 0.f);
        __hip_bfloat16 bv = __float2bfloat16(xv);
        sO[(rt * 16 + quad * 4 + rg) * OS + col] = *(short*)&bv;
      }
  }
  __syncthreads();  // also orders all waves' A-reads before in-place writes

  if constexpr (FINAL) {
    // fused 384 -> 3 projection from LDS; thread (row = t&63, o = t>>6), t<192
    if (t < 192) {
      int row = t & 63, o = t >> 6;
      int grow = row0 + row;
      if (grow < N_NODES) {
        float s = 0.f;
        #pragma unroll
        for (int kb = 0; kb < 48; ++kb) {
          short8 hv = *(const short8*)&sO[row * OS + kb * 8];
          #pragma unroll
          for (int j = 0; j < 8; ++j) s += bf16f(hv[j]) * W3[o * HID + kb * 8 + j];
        }
        out3[grow * OUT_DIM + o] = s + b3[o];
      }
    }
  } else {
    // 64 rows x 768 B out; 48 16B-chunks per row; 256 thr x 12 chunks
    #pragma unroll
    for (int it = 0; it < 12; ++it) {
      int e = t + it * 256;
      int row = e / 48, cs = e % 48;
      int grow = row0 + row;
      if (grow < N_NODES) {
        uint4 v = *(const uint4*)&sO[row * OS + cs * 8];
        *(uint4*)(out + (size_t)grow * HID + cs * 8) = v;
      }
    }
  }
}

// ------------------------- launcher -------------------------

extern "C" void kernel_launch(void* const* d_in, const int* in_sizes, int n_in,
                              void* d_out, int out_size, void* d_ws, size_t ws_size,
                              hipStream_t stream) {
  const float* x = (const float*)d_in[0];
  const int* ei = (const int*)d_in[1];
  const int* src = ei;
  const int* dst = ei + N_EDGES;
  const float* W_l0 = (const float*)d_in[2];
  const float* b_l0 = (const float*)d_in[3];
  const float* W_r0 = (const float*)d_in[4];
  const float* W_l = (const float*)d_in[5];
  const float* b_l = (const float*)d_in[6];
  const float* W_r = (const float*)d_in[7];
  const float* bn_g = (const float*)d_in[8];
  const float* bn_b = (const float*)d_in[9];
  const float* bn_m = (const float*)d_in[10];
  const float* bn_v = (const float*)d_in[11];
  const float* Wp0 = (const float*)d_in[12];
  const float* bp0 = (const float*)d_in[13];
  const float* Wp1 = (const float*)d_in[14];
  const float* bp1 = (const float*)d_in[15];
  const float* Wp2 = (const float*)d_in[16];
  const float* bp2 = (const float*)d_in[17];
  const float* pbn_g = (const float*)d_in[18];
  const float* pbn_b = (const float*)d_in[19];
  const float* pbn_m = (const float*)d_in[20];
  const float* pbn_v = (const float*)d_in[21];

  char* ws = (char*)d_ws;
  size_t off = 0;
  auto walloc = [&](size_t bytes) -> void* {
    void* p = ws + off;
    off = (off + bytes + 255) & ~(size_t)255;
    return p;
  };
  __hip_bfloat16* h   = (__hip_bfloat16*)walloc((size_t)N_NODES * HID * 2);  // 76.8 MB
  __hip_bfloat16* agg = (__hip_bfloat16*)walloc((size_t)N_NODES * HID * 2);  // 76.8 MB
  float* agg10 = (float*)agg;  // 4 MB fp32 overlay; agg not used until layer 1
  __hip_bfloat16* X2  = (__hip_bfloat16*)walloc((size_t)N_NODES * 64 * 2);   // 12.8 MB
  __hip_bfloat16* W2  = (__hip_bfloat16*)walloc((size_t)HID * 64 * 2);
  __hip_bfloat16* WlB  = (__hip_bfloat16*)walloc((size_t)(T_LAYERS - 1) * HID * HID * 2);
  __hip_bfloat16* WrB  = (__hip_bfloat16*)walloc((size_t)(T_LAYERS - 1) * HID * HID * 2);
  __hip_bfloat16* Wp0B = (__hip_bfloat16*)walloc((size_t)HID * HID * 2);
  __hip_bfloat16* Wp1B = (__hip_bfloat16*)walloc((size_t)HID * HID * 2);
  int* cnt     = (int*)walloc((size_t)N_NODES * 4);
  int* row_off = (int*)walloc((size_t)(N_NODES + 1) * 4);
  int* cursor  = (int*)walloc((size_t)N_NODES * 4);
  int* csr     = (int*)walloc((size_t)N_EDGES * 4);
  int* bsum    = (int*)walloc(4096);

  hipMemsetAsync(cnt, 0, (size_t)N_NODES * 4, stream);
  hipMemsetAsync(cursor, 0, (size_t)N_NODES * 4, stream);

  // weight prepack
  const int NW = (T_LAYERS - 1) * HID * HID;
  conv_k<<<(NW + 255) / 256, 256, 0, stream>>>(W_l, WlB, NW);
  conv_k<<<(NW + 255) / 256, 256, 0, stream>>>(W_r, WrB, NW);
  conv_k<<<(HID * HID + 255) / 256, 256, 0, stream>>>(Wp0, Wp0B, HID * HID);
  conv_k<<<(HID * HID + 255) / 256, 256, 0, stream>>>(Wp1, Wp1B, HID * HID);
  packw0_k<<<(HID * 64 + 255) / 256, 256, 0, stream>>>(W_l0, W_r0, W2);

  // CSR build
  count_k<<<(N_EDGES + 255) / 256, 256, 0, stream>>>(dst, cnt, N_EDGES);
  int P = (N_NODES + 1 + 1023) / 1024;
  scan_partial_k<<<P, 1024, 0, stream>>>(cnt, bsum, N_NODES);
  scan_small_k<<<1, 1024, 0, stream>>>(bsum, P);
  scan_final_k<<<P, 1024, 0, stream>>>(cnt, bsum, row_off, N_NODES);
  fill_k<<<(N_EDGES + 255) / 256, 256, 0, stream>>>(src, dst, row_off, cursor, csr, N_EDGES);

  const int GB = (N_NODES + 63) / 64;  // 1563 row-blocks

  // layer 0: agg10 -> pack -> MFMA GEMM (K=64: [x|agg10|pad] x [Wr0|Wl0|pad])
  agg10_k<<<(N_NODES + 7) / 8, 256, 0, stream>>>(x, row_off, csr, agg10, N_NODES);
  pack0_k<<<(N_NODES * 64 + 255) / 256, 256, 0, stream>>>(x, agg10, X2, N_NODES);
  mfma_gemm_k<64, false, 0, false><<<GB, 256, 0, stream>>>(
      X2, W2, nullptr, nullptr, b_l0, bn_g, bn_b, bn_m, bn_v, h,
      nullptr, nullptr, nullptr);

  // layers 1..4 (dual MFMA GEMM, in-place h update)
  for (int t = 1; t < T_LAYERS; ++t) {
    aggv_k<<<(N_NODES + 3) / 4, 256, 0, stream>>>(h, row_off, csr, agg, N_NODES);
    mfma_gemm_k<HID, true, 0, false><<<GB, 256, 0, stream>>>(
        agg, WlB + (size_t)(t - 1) * HID * HID,
        h,   WrB + (size_t)(t - 1) * HID * HID,
        b_l + (size_t)(t - 1) * HID,
        bn_g + (size_t)t * HID, bn_b + (size_t)t * HID,
        bn_m + (size_t)t * HID, bn_v + (size_t)t * HID,
        h, nullptr, nullptr, nullptr);
  }

  // projection MLP: proj0 in-place on h; proj1 fused with the 384->3 output
  mfma_gemm_k<HID, false, 1, false><<<GB, 256, 0, stream>>>(
      h, Wp0B, nullptr, nullptr, bp0, pbn_g, pbn_b, pbn_m, pbn_v, h,
      nullptr, nullptr, nullptr);
  mfma_gemm_k<HID, false, 1, true><<<GB, 256, 0, stream>>>(
      h, Wp1B, nullptr, nullptr, bp1, pbn_g + HID, pbn_b + HID, pbn_m + HID, pbn_v + HID, h,
      Wp2, bp2, (float*)d_out);
}

// Round 4
// 1106.187 us; speedup vs baseline: 1.6105x; 1.6105x over previous
//
#include <hip/hip_runtime.h>
#include <hip/hip_bf16.h>

#define N_NODES 100000
#define N_EDGES 300000
#define IN_DIM 10
#define HID 384
#define OUT_DIM 3
#define T_LAYERS 5
#define BN_EPS 1e-5f

typedef __attribute__((ext_vector_type(8))) short short8;
typedef __attribute__((ext_vector_type(4))) float floatx4;

__device__ __forceinline__ float bf16f(short v) {
  return __uint_as_float(((unsigned)(unsigned short)v) << 16);
}

// ------------------------- CSR build -------------------------

__global__ void count_k(const int* __restrict__ dst, int* __restrict__ cnt, int E) {
  int e = blockIdx.x * blockDim.x + threadIdx.x;
  if (e < E) atomicAdd(&cnt[dst[e]], 1);
}

__global__ void scan_partial_k(const int* __restrict__ cnt, int* __restrict__ bsum, int n) {
  int t = threadIdx.x;
  int i = blockIdx.x * 1024 + t;
  int v = (i < n) ? cnt[i] : 0;
  #pragma unroll
  for (int off = 1; off < 64; off <<= 1) v += __shfl_xor(v, off);
  __shared__ int ws[16];
  if ((t & 63) == 0) ws[t >> 6] = v;
  __syncthreads();
  if (t == 0) {
    int s = 0;
    #pragma unroll
    for (int w = 0; w < 16; ++w) s += ws[w];
    bsum[blockIdx.x] = s;
  }
}

__global__ void scan_small_k(int* __restrict__ bsum, int P) {
  __shared__ int s[1024];
  int t = threadIdx.x;
  int v = (t < P) ? bsum[t] : 0;
  s[t] = v;
  __syncthreads();
  for (int off = 1; off < 1024; off <<= 1) {
    int add = (t >= off) ? s[t - off] : 0;
    __syncthreads();
    s[t] += add;
    __syncthreads();
  }
  if (t < P) bsum[t] = s[t] - v;  // exclusive block-prefix
}

__global__ void scan_final_k(const int* __restrict__ cnt, const int* __restrict__ bsum,
                             int* __restrict__ row_off, int n) {
  int t = threadIdx.x, lane = t & 63, wv = t >> 6;
  int i = blockIdx.x * 1024 + t;
  int v = (i < n) ? cnt[i] : 0;
  int x = v;
  #pragma unroll
  for (int off = 1; off < 64; off <<= 1) {
    int y = __shfl_up(x, off);
    if (lane >= off) x += y;
  }
  __shared__ int ws[16];
  if (lane == 63) ws[wv] = x;
  __syncthreads();
  if (t == 0) {
    int a = 0;
    #pragma unroll
    for (int w = 0; w < 16; ++w) { int tmp = ws[w]; ws[w] = a; a += tmp; }
  }
  __syncthreads();
  int excl = (x - v) + ws[wv] + bsum[blockIdx.x];
  if (i <= n) row_off[i] = excl;
}

__global__ void fill_k(const int* __restrict__ src, const int* __restrict__ dst,
                       const int* __restrict__ row_off, int* __restrict__ cursor,
                       int* __restrict__ csr, int E) {
  int e = blockIdx.x * blockDim.x + threadIdx.x;
  if (e < E) {
    int d = dst[e];
    int pos = atomicAdd(&cursor[d], 1);
    csr[row_off[d] + pos] = src[e];
  }
}

// ------------------------- prepack kernels -------------------------

__global__ void conv_k(const float* __restrict__ src, __hip_bfloat16* __restrict__ dst, int n) {
  int i = blockIdx.x * blockDim.x + threadIdx.x;
  if (i < n) dst[i] = __float2bfloat16(src[i]);
}

// X2[n][64] = { x[n][0..10) , agg10[n][0..10) , 0 pad }
__global__ void pack0_k(const float* __restrict__ x, const float* __restrict__ agg10,
                        __hip_bfloat16* __restrict__ X2, int n) {
  int i = blockIdx.x * blockDim.x + threadIdx.x;
  if (i < n * 64) {
    int node = i >> 6, k = i & 63;
    float v = (k < IN_DIM) ? x[node * IN_DIM + k]
              : (k < 2 * IN_DIM) ? agg10[node * IN_DIM + (k - IN_DIM)] : 0.f;
    X2[i] = __float2bfloat16(v);
  }
}

// W2[o][64] = { W_r0 (pairs x) , W_l0 (pairs agg10) , 0 pad }
__global__ void packw0_k(const float* __restrict__ Wl, const float* __restrict__ Wr,
                         __hip_bfloat16* __restrict__ W2) {
  int i = blockIdx.x * blockDim.x + threadIdx.x;
  if (i < HID * 64) {
    int o = i >> 6, k = i & 63;
    float v = (k < IN_DIM) ? Wr[o * IN_DIM + k]
              : (k < 2 * IN_DIM) ? Wl[o * IN_DIM + (k - IN_DIM)]
              : 0.f;
    W2[i] = __float2bfloat16(v);
  }
}

// ------------------------- aggregation -------------------------

__global__ void agg10_k(const float* __restrict__ x, const int* __restrict__ row_off,
                        const int* __restrict__ csr, float* __restrict__ agg10, int n) {
  int sub = threadIdx.x >> 5;
  int lane = threadIdx.x & 31;
  int node = blockIdx.x * 8 + sub;
  if (node >= n) return;
  int s = row_off[node], e = row_off[node + 1];
  if (lane < IN_DIM) {
    float acc = 0.f;
    for (int j = s; j < e; ++j) acc += x[csr[j] * IN_DIM + lane];
    float c = (float)max(e - s, 1);
    agg10[node * IN_DIM + lane] = acc / c;
  }
}

// F=384 mean aggregation: one wave per node, lanes 0..47 hold 8 bf16 cols each.
__global__ __launch_bounds__(256) void aggv_k(const __hip_bfloat16* __restrict__ h,
                                              const int* __restrict__ row_off,
                                              const int* __restrict__ csr,
                                              __hip_bfloat16* __restrict__ agg, int n) {
  int node = blockIdx.x * 4 + (threadIdx.x >> 6);
  if (node >= n) return;
  int lane = threadIdx.x & 63;
  if (lane >= 48) return;
  int s = row_off[node], e = row_off[node + 1];
  float acc[8] = {0.f, 0.f, 0.f, 0.f, 0.f, 0.f, 0.f, 0.f};
  for (int j = s; j < e; ++j) {
    const uint4 v = *(const uint4*)(h + (size_t)csr[j] * HID + lane * 8);
    uint u0 = v.x, u1 = v.y, u2 = v.z, u3 = v.w;
    acc[0] += __uint_as_float(u0 << 16);
    acc[1] += __uint_as_float(u0 & 0xffff0000u);
    acc[2] += __uint_as_float(u1 << 16);
    acc[3] += __uint_as_float(u1 & 0xffff0000u);
    acc[4] += __uint_as_float(u2 << 16);
    acc[5] += __uint_as_float(u2 & 0xffff0000u);
    acc[6] += __uint_as_float(u3 << 16);
    acc[7] += __uint_as_float(u3 & 0xffff0000u);
  }
  float invc = 1.f / (float)max(e - s, 1);
  uint out[4];
  #pragma unroll
  for (int q = 0; q < 4; ++q) {
    __hip_bfloat16 lo = __float2bfloat16(acc[2 * q] * invc);
    __hip_bfloat16 hi = __float2bfloat16(acc[2 * q + 1] * invc);
    out[q] = (uint)(*(unsigned short*)&lo) | ((uint)(*(unsigned short*)&hi) << 16);
  }
  *(uint4*)(agg + (size_t)node * HID + lane * 8) = make_uint4(out[0], out[1], out[2], out[3]);
}

// ------------------------- MFMA GEMM, fused epilogue -------------------------
// out[i, col] = sum_k A1[i,k]*B1[col,k] (+ A2[i,k]*B2[col,k]) + bias[col]
// r10 = R0's proven staged structure (150us/dual), ONE axis changed: 8 waves
// per block (512 thr) on the same 64x384 tile -> 16 waves/CU (4/SIMD).
//  * r7-r9 post-mortem: direct global->reg fragment loads are 16-segment
//    gathers (16 rows x 64B per instruction) — 16 transactions vs 1. LDS
//    staging (coalesced dwordx4 in, LDS broadcast out) is what the MFMA
//    fragment layout REQUIRES for bandwidth; de-staging regressed 150->292us.
//    This kernel restores the staged loop byte-for-byte (2 syncthreads/chunk,
//    no inline asm, no prefetch regs across MFMA — r6 lesson) and only widens
//    the block: each wave owns 64x48 (acc[4][3] = 48 regs, half of R0), and
//    per-thread staging halves (7 vs 14 loads/chunk). LDS 56KB -> 2 blocks/CU.
//  * Spill tripwire: WRITE_SIZE must stay 75 MB.
// Epilogue: pack bf16 to LDS (stride 392), coalesced dwordx4 out.
// In-place safe (out == A1 or A2): block reads only its own 64 rows.
template <int KTOT, bool DUAL, int EPI, bool FINAL>
__global__ __launch_bounds__(512, 4) void mfma_gemm_k(
    const __hip_bfloat16* __restrict__ A1, const __hip_bfloat16* __restrict__ B1,
    const __hip_bfloat16* __restrict__ A2, const __hip_bfloat16* __restrict__ B2,
    const float* __restrict__ bias,
    const float* __restrict__ bng, const float* __restrict__ bnb,
    const float* __restrict__ bnm, const float* __restrict__ bnv,
    __hip_bfloat16* __restrict__ out,
    const float* __restrict__ W3, const float* __restrict__ b3,
    float* __restrict__ out3) {
  __shared__ alignas(16) short smem[64 * 64 + HID * 64];  // 57344 B
  short* sA = smem;
  short* sB = smem + 64 * 64;

  const int t = threadIdx.x;
  const int lane = t & 63;
  const int wv = t >> 6;        // 0..7
  const int n16 = lane & 15;
  const int quad = lane >> 4;
  const int row0 = blockIdx.x * 64;

  floatx4 acc[4][3];
  #pragma unroll
  for (int rt = 0; rt < 4; ++rt)
    #pragma unroll
    for (int ct = 0; ct < 3; ++ct) acc[rt][ct] = (floatx4)0.f;

  constexpr int KCH = KTOT / 64;
  constexpr int NCH = DUAL ? 2 * KCH : KCH;
  for (int c = 0; c < NCH; ++c) {
    const __hip_bfloat16* Ap;
    const __hip_bfloat16* Bp;
    int kc;
    if (!DUAL || c < KCH) { Ap = A1; Bp = B1; kc = c * 64; }
    else                  { Ap = A2; Bp = B2; kc = (c - KCH) * 64; }
    // stage A tile: 64 rows x 64 k (1 x 16B per thread)
    {
      int row = t >> 3, g = t & 7;
      int grow = min(row0 + row, N_NODES - 1);  // clamp ragged last block
      uint4 v = *(const uint4*)(Ap + (size_t)grow * KTOT + kc + g * 8);
      *(uint4*)&sA[row * 64 + ((g ^ (row & 7)) * 8)] = v;
    }
    // stage B tile: 384 cols x 64 k (6 x 16B per thread)
    #pragma unroll
    for (int it = 0; it < 6; ++it) {
      int e = t + it * 512;
      int col = e >> 3, g = e & 7;
      uint4 v = *(const uint4*)(Bp + (size_t)col * KTOT + kc + g * 8);
      *(uint4*)&sB[col * 64 + ((g ^ (col & 7)) * 8)] = v;
    }
    __syncthreads();
    #pragma unroll
    for (int kh = 0; kh < 2; ++kh) {
      short8 af[4], bf[3];
      int g = kh * 4 + quad;
      #pragma unroll
      for (int rt = 0; rt < 4; ++rt) {
        int r = rt * 16 + n16;
        af[rt] = *(const short8*)&sA[r * 64 + ((g ^ (r & 7)) * 8)];
      }
      #pragma unroll
      for (int ct = 0; ct < 3; ++ct) {
        int cl = wv * 48 + ct * 16 + n16;
        bf[ct] = *(const short8*)&sB[cl * 64 + ((g ^ (cl & 7)) * 8)];
      }
      #pragma unroll
      for (int rt = 0; rt < 4; ++rt)
        #pragma unroll
        for (int ct = 0; ct < 3; ++ct)
          acc[rt][ct] = __builtin_amdgcn_mfma_f32_16x16x32_bf16(af[rt], bf[ct], acc[rt][ct], 0, 0, 0);
    }
    __syncthreads();
  }

  // ---- epilogue ----
  int gc[3];
  #pragma unroll
  for (int ct = 0; ct < 3; ++ct) {
    gc[ct] = wv * 48 + ct * 16 + n16;
    float bs = bias[gc[ct]];
    #pragma unroll
    for (int rt = 0; rt < 4; ++rt)
      #pragma unroll
      for (int rg = 0; rg < 4; ++rg) acc[rt][ct][rg] += bs;
  }

  if constexpr (EPI == 0) {
    // row L2 norm: 16-lane shfl partials, cross-wave (8 waves) via LDS
    float* red = (float*)smem;  // 512 floats
    float inv[4][4];
    #pragma unroll
    for (int rt = 0; rt < 4; ++rt)
      #pragma unroll
      for (int rg = 0; rg < 4; ++rg) {
        float s = 0.f;
        #pragma unroll
        for (int ct = 0; ct < 3; ++ct) s += acc[rt][ct][rg] * acc[rt][ct][rg];
        #pragma unroll
        for (int off = 1; off < 16; off <<= 1) s += __shfl_xor(s, off);
        if (n16 == 0) red[wv * 64 + rt * 16 + quad * 4 + rg] = s;
      }
    __syncthreads();
    #pragma unroll
    for (int rt = 0; rt < 4; ++rt)
      #pragma unroll
      for (int rg = 0; rg < 4; ++rg) {
        int rl = rt * 16 + quad * 4 + rg;
        float ss = 0.f;
        #pragma unroll
        for (int w = 0; w < 8; ++w) ss += red[w * 64 + rl];
        inv[rt][rg] = 1.f / fmaxf(sqrtf(ss), 1e-12f);
      }
    #pragma unroll
    for (int rt = 0; rt < 4; ++rt)
      #pragma unroll
      for (int ct = 0; ct < 3; ++ct)
        #pragma unroll
        for (int rg = 0; rg < 4; ++rg) acc[rt][ct][rg] *= inv[rt][rg];
    __syncthreads();  // red reads done before smem reused as sO
  }

  // BN + activation, pack bf16 into LDS (row stride 392 shorts)
  constexpr int OS = 392;  // 64 * 392 * 2 B = 50176 B <= 56 KB
  short* sO = smem;
  #pragma unroll
  for (int ct = 0; ct < 3; ++ct) {
    int col = gc[ct];
    float sc = bng[col] * rsqrtf(bnv[col] + BN_EPS);
    float sh = bnb[col] - bnm[col] * sc;
    #pragma unroll
    for (int rt = 0; rt < 4; ++rt)
      #pragma unroll
      for (int rg = 0; rg < 4; ++rg) {
        float xv = acc[rt][ct][rg] * sc + sh;
        if constexpr (EPI == 0)
          xv = xv > 0.f ? xv : expm1f(xv);
        else
          xv = fmaxf(xv, 0.f);
        __hip_bfloat16 bv = __float2bfloat16(xv);
        sO[(rt * 16 + quad * 4 + rg) * OS + col] = *(short*)&bv;
      }
  }
  __syncthreads();

  if constexpr (FINAL) {
    // fused 384 -> 3 projection from LDS; thread (row = t&63, o = t>>6), t<192
    if (t < 192) {
      int row = t & 63, o = t >> 6;
      int grow = row0 + row;
      if (grow < N_NODES) {
        float s = 0.f;
        #pragma unroll
        for (int kb = 0; kb < 48; ++kb) {
          short8 hv = *(const short8*)&sO[row * OS + kb * 8];
          #pragma unroll
          for (int j = 0; j < 8; ++j) s += bf16f(hv[j]) * W3[o * HID + kb * 8 + j];
        }
        out3[grow * OUT_DIM + o] = s + b3[o];
      }
    }
  } else {
    // 64 rows x 768 B out; 48 16B-chunks per row; 512 thr x 6 chunks
    #pragma unroll
    for (int it = 0; it < 6; ++it) {
      int e = t + it * 512;
      int row = e / 48, cs = e % 48;
      int grow = row0 + row;
      if (grow < N_NODES) {
        uint4 v = *(const uint4*)&sO[row * OS + cs * 8];
        *(uint4*)(out + (size_t)grow * HID + cs * 8) = v;
      }
    }
  }
}

// ------------------------- launcher -------------------------

extern "C" void kernel_launch(void* const* d_in, const int* in_sizes, int n_in,
                              void* d_out, int out_size, void* d_ws, size_t ws_size,
                              hipStream_t stream) {
  const float* x = (const float*)d_in[0];
  const int* ei = (const int*)d_in[1];
  const int* src = ei;
  const int* dst = ei + N_EDGES;
  const float* W_l0 = (const float*)d_in[2];
  const float* b_l0 = (const float*)d_in[3];
  const float* W_r0 = (const float*)d_in[4];
  const float* W_l = (const float*)d_in[5];
  const float* b_l = (const float*)d_in[6];
  const float* W_r = (const float*)d_in[7];
  const float* bn_g = (const float*)d_in[8];
  const float* bn_b = (const float*)d_in[9];
  const float* bn_m = (const float*)d_in[10];
  const float* bn_v = (const float*)d_in[11];
  const float* Wp0 = (const float*)d_in[12];
  const float* bp0 = (const float*)d_in[13];
  const float* Wp1 = (const float*)d_in[14];
  const float* bp1 = (const float*)d_in[15];
  const float* Wp2 = (const float*)d_in[16];
  const float* bp2 = (const float*)d_in[17];
  const float* pbn_g = (const float*)d_in[18];
  const float* pbn_b = (const float*)d_in[19];
  const float* pbn_m = (const float*)d_in[20];
  const float* pbn_v = (const float*)d_in[21];

  char* ws = (char*)d_ws;
  size_t off = 0;
  auto walloc = [&](size_t bytes) -> void* {
    void* p = ws + off;
    off = (off + bytes + 255) & ~(size_t)255;
    return p;
  };
  __hip_bfloat16* h   = (__hip_bfloat16*)walloc((size_t)N_NODES * HID * 2);  // 76.8 MB
  __hip_bfloat16* agg = (__hip_bfloat16*)walloc((size_t)N_NODES * HID * 2);  // 76.8 MB
  float* agg10 = (float*)agg;  // 4 MB fp32 overlay; agg not used until layer 1
  __hip_bfloat16* X2  = (__hip_bfloat16*)walloc((size_t)N_NODES * 64 * 2);   // 12.8 MB
  __hip_bfloat16* W2  = (__hip_bfloat16*)walloc((size_t)HID * 64 * 2);
  __hip_bfloat16* WlB  = (__hip_bfloat16*)walloc((size_t)(T_LAYERS - 1) * HID * HID * 2);
  __hip_bfloat16* WrB  = (__hip_bfloat16*)walloc((size_t)(T_LAYERS - 1) * HID * HID * 2);
  __hip_bfloat16* Wp0B = (__hip_bfloat16*)walloc((size_t)HID * HID * 2);
  __hip_bfloat16* Wp1B = (__hip_bfloat16*)walloc((size_t)HID * HID * 2);
  int* cnt     = (int*)walloc((size_t)N_NODES * 4);
  int* row_off = (int*)walloc((size_t)(N_NODES + 1) * 4);
  int* cursor  = (int*)walloc((size_t)N_NODES * 4);
  int* csr     = (int*)walloc((size_t)N_EDGES * 4);
  int* bsum    = (int*)walloc(4096);

  hipMemsetAsync(cnt, 0, (size_t)N_NODES * 4, stream);
  hipMemsetAsync(cursor, 0, (size_t)N_NODES * 4, stream);

  // weight prepack
  const int NW = (T_LAYERS - 1) * HID * HID;
  conv_k<<<(NW + 255) / 256, 256, 0, stream>>>(W_l, WlB, NW);
  conv_k<<<(NW + 255) / 256, 256, 0, stream>>>(W_r, WrB, NW);
  conv_k<<<(HID * HID + 255) / 256, 256, 0, stream>>>(Wp0, Wp0B, HID * HID);
  conv_k<<<(HID * HID + 255) / 256, 256, 0, stream>>>(Wp1, Wp1B, HID * HID);
  packw0_k<<<(HID * 64 + 255) / 256, 256, 0, stream>>>(W_l0, W_r0, W2);

  // CSR build
  count_k<<<(N_EDGES + 255) / 256, 256, 0, stream>>>(dst, cnt, N_EDGES);
  int P = (N_NODES + 1 + 1023) / 1024;
  scan_partial_k<<<P, 1024, 0, stream>>>(cnt, bsum, N_NODES);
  scan_small_k<<<1, 1024, 0, stream>>>(bsum, P);
  scan_final_k<<<P, 1024, 0, stream>>>(cnt, bsum, row_off, N_NODES);
  fill_k<<<(N_EDGES + 255) / 256, 256, 0, stream>>>(src, dst, row_off, cursor, csr, N_EDGES);

  const int GB = (N_NODES + 63) / 64;  // 1563 row-blocks

  // layer 0: agg10 -> pack -> MFMA GEMM (K=64: [x|agg10|pad] x [Wr0|Wl0|pad])
  agg10_k<<<(N_NODES + 7) / 8, 256, 0, stream>>>(x, row_off, csr, agg10, N_NODES);
  pack0_k<<<(N_NODES * 64 + 255) / 256, 256, 0, stream>>>(x, agg10, X2, N_NODES);
  mfma_gemm_k<64, false, 0, false><<<GB, 512, 0, stream>>>(
      X2, W2, nullptr, nullptr, b_l0, bn_g, bn_b, bn_m, bn_v, h,
      nullptr, nullptr, nullptr);

  // layers 1..4 (dual MFMA GEMM, in-place h update)
  for (int t = 1; t < T_LAYERS; ++t) {
    aggv_k<<<(N_NODES + 3) / 4, 256, 0, stream>>>(h, row_off, csr, agg, N_NODES);
    mfma_gemm_k<HID, true, 0, false><<<GB, 512, 0, stream>>>(
        agg, WlB + (size_t)(t - 1) * HID * HID,
        h,   WrB + (size_t)(t - 1) * HID * HID,
        b_l + (size_t)(t - 1) * HID,
        bn_g + (size_t)t * HID, bn_b + (size_t)t * HID,
        bn_m + (size_t)t * HID, bn_v + (size_t)t * HID,
        h, nullptr, nullptr, nullptr);
  }

  // projection MLP: proj0 in-place on h; proj1 fused with the 384->3 output
  mfma_gemm_k<HID, false, 1, false><<<GB, 512, 0, stream>>>(
      h, Wp0B, nullptr, nullptr, bp0, pbn_g, pbn_b, pbn_m, pbn_v, h,
      nullptr, nullptr, nullptr);
  mfma_gemm_k<HID, false, 1, true><<<GB, 512, 0, stream>>>(
      h, Wp1B, nullptr, nullptr, bp1, pbn_g + HID, pbn_b + HID, pbn_m + HID, pbn_v + HID, h,
      Wp2, bp2, (float*)d_out);
}

// Round 5
// 1072.196 us; speedup vs baseline: 1.6615x; 1.0317x over previous
//
#include <hip/hip_runtime.h>
#include <hip/hip_bf16.h>

#define N_NODES 100000
#define N_EDGES 300000
#define IN_DIM 10
#define HID 384
#define OUT_DIM 3
#define T_LAYERS 5
#define BN_EPS 1e-5f

typedef __attribute__((ext_vector_type(8))) short short8;
typedef __attribute__((ext_vector_type(4))) float floatx4;

__device__ __forceinline__ float bf16f(short v) {
  return __uint_as_float(((unsigned)(unsigned short)v) << 16);
}

// async global->LDS, 16 B per lane; dst is wave-uniform base, lane l lands at
// dst + l*16 (linear). Swizzle lives on the SOURCE address (m173 pattern).
__device__ __forceinline__ void gld_lds16(const void* g, void* l) {
  __builtin_amdgcn_global_load_lds(
      (const __attribute__((address_space(1))) void*)g,
      (__attribute__((address_space(3))) void*)l, 16, 0, 0);
}

// ------------------------- CSR build -------------------------

__global__ void count_k(const int* __restrict__ dst, int* __restrict__ cnt, int E) {
  int e = blockIdx.x * blockDim.x + threadIdx.x;
  if (e < E) atomicAdd(&cnt[dst[e]], 1);
}

__global__ void scan_partial_k(const int* __restrict__ cnt, int* __restrict__ bsum, int n) {
  int t = threadIdx.x;
  int i = blockIdx.x * 1024 + t;
  int v = (i < n) ? cnt[i] : 0;
  #pragma unroll
  for (int off = 1; off < 64; off <<= 1) v += __shfl_xor(v, off);
  __shared__ int ws[16];
  if ((t & 63) == 0) ws[t >> 6] = v;
  __syncthreads();
  if (t == 0) {
    int s = 0;
    #pragma unroll
    for (int w = 0; w < 16; ++w) s += ws[w];
    bsum[blockIdx.x] = s;
  }
}

__global__ void scan_small_k(int* __restrict__ bsum, int P) {
  __shared__ int s[1024];
  int t = threadIdx.x;
  int v = (t < P) ? bsum[t] : 0;
  s[t] = v;
  __syncthreads();
  for (int off = 1; off < 1024; off <<= 1) {
    int add = (t >= off) ? s[t - off] : 0;
    __syncthreads();
    s[t] += add;
    __syncthreads();
  }
  if (t < P) bsum[t] = s[t] - v;  // exclusive block-prefix
}

__global__ void scan_final_k(const int* __restrict__ cnt, const int* __restrict__ bsum,
                             int* __restrict__ row_off, int n) {
  int t = threadIdx.x, lane = t & 63, wv = t >> 6;
  int i = blockIdx.x * 1024 + t;
  int v = (i < n) ? cnt[i] : 0;
  int x = v;
  #pragma unroll
  for (int off = 1; off < 64; off <<= 1) {
    int y = __shfl_up(x, off);
    if (lane >= off) x += y;
  }
  __shared__ int ws[16];
  if (lane == 63) ws[wv] = x;
  __syncthreads();
  if (t == 0) {
    int a = 0;
    #pragma unroll
    for (int w = 0; w < 16; ++w) { int tmp = ws[w]; ws[w] = a; a += tmp; }
  }
  __syncthreads();
  int excl = (x - v) + ws[wv] + bsum[blockIdx.x];
  if (i <= n) row_off[i] = excl;
}

__global__ void fill_k(const int* __restrict__ src, const int* __restrict__ dst,
                       const int* __restrict__ row_off, int* __restrict__ cursor,
                       int* __restrict__ csr, int E) {
  int e = blockIdx.x * blockDim.x + threadIdx.x;
  if (e < E) {
    int d = dst[e];
    int pos = atomicAdd(&cursor[d], 1);
    csr[row_off[d] + pos] = src[e];
  }
}

// ------------------------- prepack kernels -------------------------

__global__ void conv_k(const float* __restrict__ src, __hip_bfloat16* __restrict__ dst, int n) {
  int i = blockIdx.x * blockDim.x + threadIdx.x;
  if (i < n) dst[i] = __float2bfloat16(src[i]);
}

// X2[n][64] = { x[n][0..10) , agg10[n][0..10) , 0 pad }
__global__ void pack0_k(const float* __restrict__ x, const float* __restrict__ agg10,
                        __hip_bfloat16* __restrict__ X2, int n) {
  int i = blockIdx.x * blockDim.x + threadIdx.x;
  if (i < n * 64) {
    int node = i >> 6, k = i & 63;
    float v = (k < IN_DIM) ? x[node * IN_DIM + k]
              : (k < 2 * IN_DIM) ? agg10[node * IN_DIM + (k - IN_DIM)] : 0.f;
    X2[i] = __float2bfloat16(v);
  }
}

// W2[o][64] = { W_r0 (pairs x) , W_l0 (pairs agg10) , 0 pad }
__global__ void packw0_k(const float* __restrict__ Wl, const float* __restrict__ Wr,
                         __hip_bfloat16* __restrict__ W2) {
  int i = blockIdx.x * blockDim.x + threadIdx.x;
  if (i < HID * 64) {
    int o = i >> 6, k = i & 63;
    float v = (k < IN_DIM) ? Wr[o * IN_DIM + k]
              : (k < 2 * IN_DIM) ? Wl[o * IN_DIM + (k - IN_DIM)]
              : 0.f;
    W2[i] = __float2bfloat16(v);
  }
}

// ------------------------- aggregation -------------------------

__global__ void agg10_k(const float* __restrict__ x, const int* __restrict__ row_off,
                        const int* __restrict__ csr, float* __restrict__ agg10, int n) {
  int sub = threadIdx.x >> 5;
  int lane = threadIdx.x & 31;
  int node = blockIdx.x * 8 + sub;
  if (node >= n) return;
  int s = row_off[node], e = row_off[node + 1];
  if (lane < IN_DIM) {
    float acc = 0.f;
    for (int j = s; j < e; ++j) acc += x[csr[j] * IN_DIM + lane];
    float c = (float)max(e - s, 1);
    agg10[node * IN_DIM + lane] = acc / c;
  }
}

// F=384 mean aggregation: one wave per node, lanes 0..47 hold 8 bf16 cols each.
__global__ __launch_bounds__(256) void aggv_k(const __hip_bfloat16* __restrict__ h,
                                              const int* __restrict__ row_off,
                                              const int* __restrict__ csr,
                                              __hip_bfloat16* __restrict__ agg, int n) {
  int node = blockIdx.x * 4 + (threadIdx.x >> 6);
  if (node >= n) return;
  int lane = threadIdx.x & 63;
  if (lane >= 48) return;
  int s = row_off[node], e = row_off[node + 1];
  float acc[8] = {0.f, 0.f, 0.f, 0.f, 0.f, 0.f, 0.f, 0.f};
  for (int j = s; j < e; ++j) {
    const uint4 v = *(const uint4*)(h + (size_t)csr[j] * HID + lane * 8);
    uint u0 = v.x, u1 = v.y, u2 = v.z, u3 = v.w;
    acc[0] += __uint_as_float(u0 << 16);
    acc[1] += __uint_as_float(u0 & 0xffff0000u);
    acc[2] += __uint_as_float(u1 << 16);
    acc[3] += __uint_as_float(u1 & 0xffff0000u);
    acc[4] += __uint_as_float(u2 << 16);
    acc[5] += __uint_as_float(u2 & 0xffff0000u);
    acc[6] += __uint_as_float(u3 << 16);
    acc[7] += __uint_as_float(u3 & 0xffff0000u);
  }
  float invc = 1.f / (float)max(e - s, 1);
  uint out[4];
  #pragma unroll
  for (int q = 0; q < 4; ++q) {
    __hip_bfloat16 lo = __float2bfloat16(acc[2 * q] * invc);
    __hip_bfloat16 hi = __float2bfloat16(acc[2 * q + 1] * invc);
    out[q] = (uint)(*(unsigned short*)&lo) | ((uint)(*(unsigned short*)&hi) << 16);
  }
  *(uint4*)(agg + (size_t)node * HID + lane * 8) = make_uint4(out[0], out[1], out[2], out[3]);
}

// ------------------------- MFMA GEMM, fused epilogue -------------------------
// out[i, col] = sum_k A1[i,k]*B1[col,k] (+ A2[i,k]*B2[col,k]) + bias[col]
// r11 = r10 (512 thr, 8 waves, 64x384 tile, 2-syncthreads staged loop) with
// the staging VGPR round-trip replaced by global_load_lds width-16.
//  * r10 post-mortem: at __launch_bounds__(512,4) the unified VGPR+AGPR cap
//    is 128/wave; reg-staging temps (6 uint4 B + 1 A + addr ~30 regs) pushed
//    the body over -> ~64 B/thread scratch spill (WRITE_SIZE 75->125 MB,
//    FETCH 84->111 MB, the exact tripwire). Occupancy doubled but the gain
//    was eaten by scratch round-trips (147 vs 150 us).
//  * gld_lds eliminates the staging registers entirely (documented ladder
//    step m97/m151). LDS dest is linear per wave-instruction; the XOR
//    swizzle is applied to the per-lane SOURCE address (inverse swizzle,
//    m173 — functionally verified in r7). Read side unchanged.
//  * __syncthreads() x2 per chunk unchanged (emits the vmcnt(0) drain that
//    makes gld_lds data visible).  No inline asm, no reg prefetch (r6/r8).
//  * Budget: 48 AGPR acc + 28 frag + ~16 addr ~= 95-110 <= 128 -> no spill.
// Epilogue: pack bf16 to LDS (stride 392), coalesced dwordx4 out.
// In-place safe (out == A1 or A2): block reads only its own 64 rows.
template <int KTOT, bool DUAL, int EPI, bool FINAL>
__global__ __launch_bounds__(512, 4) void mfma_gemm_k(
    const __hip_bfloat16* __restrict__ A1, const __hip_bfloat16* __restrict__ B1,
    const __hip_bfloat16* __restrict__ A2, const __hip_bfloat16* __restrict__ B2,
    const float* __restrict__ bias,
    const float* __restrict__ bng, const float* __restrict__ bnb,
    const float* __restrict__ bnm, const float* __restrict__ bnv,
    __hip_bfloat16* __restrict__ out,
    const float* __restrict__ W3, const float* __restrict__ b3,
    float* __restrict__ out3) {
  __shared__ alignas(16) short smem[64 * 64 + HID * 64];  // 57344 B
  short* sA = smem;
  short* sB = smem + 64 * 64;

  const int t = threadIdx.x;
  const int lane = t & 63;
  const int wv = t >> 6;        // 0..7
  const int n16 = lane & 15;
  const int quad = lane >> 4;
  const int row0 = blockIdx.x * 64;

  // ---- staging geometry (per-thread constant source offsets) ----
  // A: one gld_lds per wave covers rows wv*8..wv*8+7 (64 rows total).
  //    LDS short idx = wv*512 + lane*8 + j -> row = wv*8 + (lane>>3),
  //    slot = lane&7 ; source granule g = slot ^ (row&7) (inverse of read).
  const int aRow = t >> 3;                  // 0..63
  const int aG = (t & 7) ^ (aRow & 7);
  const int aOff = min(row0 + aRow, N_NODES - 1) * KTOT + aG * 8;  // elements
  // B: 6 gld_lds per wave, instruction j = wv*6+it covers cols j*8..j*8+7.
  int bOff[6];
  #pragma unroll
  for (int it = 0; it < 6; ++it) {
    int col = (wv * 6 + it) * 8 + (lane >> 3);
    int g = (lane & 7) ^ (col & 7);
    bOff[it] = col * KTOT + g * 8;  // elements
  }

  floatx4 acc[4][3];
  #pragma unroll
  for (int rt = 0; rt < 4; ++rt)
    #pragma unroll
    for (int ct = 0; ct < 3; ++ct) acc[rt][ct] = (floatx4)0.f;

  constexpr int KCH = KTOT / 64;
  constexpr int NCH = DUAL ? 2 * KCH : KCH;
  for (int c = 0; c < NCH; ++c) {
    const __hip_bfloat16* Ap;
    const __hip_bfloat16* Bp;
    int kc;
    if (!DUAL || c < KCH) { Ap = A1; Bp = B1; kc = c * 64; }
    else                  { Ap = A2; Bp = B2; kc = (c - KCH) * 64; }
    // stage A tile: 1 gld_lds per wave (8 KB total)
    gld_lds16(Ap + aOff + kc, sA + wv * 512);
    // stage B tile: 6 gld_lds per wave (48 KB total)
    #pragma unroll
    for (int it = 0; it < 6; ++it)
      gld_lds16(Bp + bOff[it] + kc, sB + (wv * 6 + it) * 512);
    __syncthreads();
    #pragma unroll
    for (int kh = 0; kh < 2; ++kh) {
      short8 af[4], bf[3];
      int g = kh * 4 + quad;
      #pragma unroll
      for (int rt = 0; rt < 4; ++rt) {
        int r = rt * 16 + n16;
        af[rt] = *(const short8*)&sA[r * 64 + ((g ^ (r & 7)) * 8)];
      }
      #pragma unroll
      for (int ct = 0; ct < 3; ++ct) {
        int cl = wv * 48 + ct * 16 + n16;
        bf[ct] = *(const short8*)&sB[cl * 64 + ((g ^ (cl & 7)) * 8)];
      }
      #pragma unroll
      for (int rt = 0; rt < 4; ++rt)
        #pragma unroll
        for (int ct = 0; ct < 3; ++ct)
          acc[rt][ct] = __builtin_amdgcn_mfma_f32_16x16x32_bf16(af[rt], bf[ct], acc[rt][ct], 0, 0, 0);
    }
    __syncthreads();
  }

  // ---- epilogue ----
  int gc[3];
  #pragma unroll
  for (int ct = 0; ct < 3; ++ct) {
    gc[ct] = wv * 48 + ct * 16 + n16;
    float bs = bias[gc[ct]];
    #pragma unroll
    for (int rt = 0; rt < 4; ++rt)
      #pragma unroll
      for (int rg = 0; rg < 4; ++rg) acc[rt][ct][rg] += bs;
  }

  if constexpr (EPI == 0) {
    // row L2 norm: 16-lane shfl partials, cross-wave (8 waves) via LDS
    float* red = (float*)smem;  // 512 floats
    float inv[4][4];
    #pragma unroll
    for (int rt = 0; rt < 4; ++rt)
      #pragma unroll
      for (int rg = 0; rg < 4; ++rg) {
        float s = 0.f;
        #pragma unroll
        for (int ct = 0; ct < 3; ++ct) s += acc[rt][ct][rg] * acc[rt][ct][rg];
        #pragma unroll
        for (int off = 1; off < 16; off <<= 1) s += __shfl_xor(s, off);
        if (n16 == 0) red[wv * 64 + rt * 16 + quad * 4 + rg] = s;
      }
    __syncthreads();
    #pragma unroll
    for (int rt = 0; rt < 4; ++rt)
      #pragma unroll
      for (int rg = 0; rg < 4; ++rg) {
        int rl = rt * 16 + quad * 4 + rg;
        float ss = 0.f;
        #pragma unroll
        for (int w = 0; w < 8; ++w) ss += red[w * 64 + rl];
        inv[rt][rg] = 1.f / fmaxf(sqrtf(ss), 1e-12f);
      }
    #pragma unroll
    for (int rt = 0; rt < 4; ++rt)
      #pragma unroll
      for (int ct = 0; ct < 3; ++ct)
        #pragma unroll
        for (int rg = 0; rg < 4; ++rg) acc[rt][ct][rg] *= inv[rt][rg];
    __syncthreads();  // red reads done before smem reused as sO
  }

  // BN + activation, pack bf16 into LDS (row stride 392 shorts)
  constexpr int OS = 392;  // 64 * 392 * 2 B = 50176 B <= 56 KB
  short* sO = smem;
  #pragma unroll
  for (int ct = 0; ct < 3; ++ct) {
    int col = gc[ct];
    float sc = bng[col] * rsqrtf(bnv[col] + BN_EPS);
    float sh = bnb[col] - bnm[col] * sc;
    #pragma unroll
    for (int rt = 0; rt < 4; ++rt)
      #pragma unroll
      for (int rg = 0; rg < 4; ++rg) {
        float xv = acc[rt][ct][rg] * sc + sh;
        if constexpr (EPI == 0)
          xv = xv > 0.f ? xv : expm1f(xv);
        else
          xv = fmaxf(xv, 0.f);
        __hip_bfloat16 bv = __float2bfloat16(xv);
        sO[(rt * 16 + quad * 4 + rg) * OS + col] = *(short*)&bv;
      }
  }
  __syncthreads();

  if constexpr (FINAL) {
    // fused 384 -> 3 projection from LDS; thread (row = t&63, o = t>>6), t<192
    if (t < 192) {
      int row = t & 63, o = t >> 6;
      int grow = row0 + row;
      if (grow < N_NODES) {
        float s = 0.f;
        #pragma unroll
        for (int kb = 0; kb < 48; ++kb) {
          short8 hv = *(const short8*)&sO[row * OS + kb * 8];
          #pragma unroll
          for (int j = 0; j < 8; ++j) s += bf16f(hv[j]) * W3[o * HID + kb * 8 + j];
        }
        out3[grow * OUT_DIM + o] = s + b3[o];
      }
    }
  } else {
    // 64 rows x 768 B out; 48 16B-chunks per row; 512 thr x 6 chunks
    #pragma unroll
    for (int it = 0; it < 6; ++it) {
      int e = t + it * 512;
      int row = e / 48, cs = e % 48;
      int grow = row0 + row;
      if (grow < N_NODES) {
        uint4 v = *(const uint4*)&sO[row * OS + cs * 8];
        *(uint4*)(out + (size_t)grow * HID + cs * 8) = v;
      }
    }
  }
}

// ------------------------- launcher -------------------------

extern "C" void kernel_launch(void* const* d_in, const int* in_sizes, int n_in,
                              void* d_out, int out_size, void* d_ws, size_t ws_size,
                              hipStream_t stream) {
  const float* x = (const float*)d_in[0];
  const int* ei = (const int*)d_in[1];
  const int* src = ei;
  const int* dst = ei + N_EDGES;
  const float* W_l0 = (const float*)d_in[2];
  const float* b_l0 = (const float*)d_in[3];
  const float* W_r0 = (const float*)d_in[4];
  const float* W_l = (const float*)d_in[5];
  const float* b_l = (const float*)d_in[6];
  const float* W_r = (const float*)d_in[7];
  const float* bn_g = (const float*)d_in[8];
  const float* bn_b = (const float*)d_in[9];
  const float* bn_m = (const float*)d_in[10];
  const float* bn_v = (const float*)d_in[11];
  const float* Wp0 = (const float*)d_in[12];
  const float* bp0 = (const float*)d_in[13];
  const float* Wp1 = (const float*)d_in[14];
  const float* bp1 = (const float*)d_in[15];
  const float* Wp2 = (const float*)d_in[16];
  const float* bp2 = (const float*)d_in[17];
  const float* pbn_g = (const float*)d_in[18];
  const float* pbn_b = (const float*)d_in[19];
  const float* pbn_m = (const float*)d_in[20];
  const float* pbn_v = (const float*)d_in[21];

  char* ws = (char*)d_ws;
  size_t off = 0;
  auto walloc = [&](size_t bytes) -> void* {
    void* p = ws + off;
    off = (off + bytes + 255) & ~(size_t)255;
    return p;
  };
  __hip_bfloat16* h   = (__hip_bfloat16*)walloc((size_t)N_NODES * HID * 2);  // 76.8 MB
  __hip_bfloat16* agg = (__hip_bfloat16*)walloc((size_t)N_NODES * HID * 2);  // 76.8 MB
  float* agg10 = (float*)agg;  // 4 MB fp32 overlay; agg not used until layer 1
  __hip_bfloat16* X2  = (__hip_bfloat16*)walloc((size_t)N_NODES * 64 * 2);   // 12.8 MB
  __hip_bfloat16* W2  = (__hip_bfloat16*)walloc((size_t)HID * 64 * 2);
  __hip_bfloat16* WlB  = (__hip_bfloat16*)walloc((size_t)(T_LAYERS - 1) * HID * HID * 2);
  __hip_bfloat16* WrB  = (__hip_bfloat16*)walloc((size_t)(T_LAYERS - 1) * HID * HID * 2);
  __hip_bfloat16* Wp0B = (__hip_bfloat16*)walloc((size_t)HID * HID * 2);
  __hip_bfloat16* Wp1B = (__hip_bfloat16*)walloc((size_t)HID * HID * 2);
  int* cnt     = (int*)walloc((size_t)N_NODES * 4);
  int* row_off = (int*)walloc((size_t)(N_NODES + 1) * 4);
  int* cursor  = (int*)walloc((size_t)N_NODES * 4);
  int* csr     = (int*)walloc((size_t)N_EDGES * 4);
  int* bsum    = (int*)walloc(4096);

  hipMemsetAsync(cnt, 0, (size_t)N_NODES * 4, stream);
  hipMemsetAsync(cursor, 0, (size_t)N_NODES * 4, stream);

  // weight prepack
  const int NW = (T_LAYERS - 1) * HID * HID;
  conv_k<<<(NW + 255) / 256, 256, 0, stream>>>(W_l, WlB, NW);
  conv_k<<<(NW + 255) / 256, 256, 0, stream>>>(W_r, WrB, NW);
  conv_k<<<(HID * HID + 255) / 256, 256, 0, stream>>>(Wp0, Wp0B, HID * HID);
  conv_k<<<(HID * HID + 255) / 256, 256, 0, stream>>>(Wp1, Wp1B, HID * HID);
  packw0_k<<<(HID * 64 + 255) / 256, 256, 0, stream>>>(W_l0, W_r0, W2);

  // CSR build
  count_k<<<(N_EDGES + 255) / 256, 256, 0, stream>>>(dst, cnt, N_EDGES);
  int P = (N_NODES + 1 + 1023) / 1024;
  scan_partial_k<<<P, 1024, 0, stream>>>(cnt, bsum, N_NODES);
  scan_small_k<<<1, 1024, 0, stream>>>(bsum, P);
  scan_final_k<<<P, 1024, 0, stream>>>(cnt, bsum, row_off, N_NODES);
  fill_k<<<(N_EDGES + 255) / 256, 256, 0, stream>>>(src, dst, row_off, cursor, csr, N_EDGES);

  const int GB = (N_NODES + 63) / 64;  // 1563 row-blocks

  // layer 0: agg10 -> pack -> MFMA GEMM (K=64: [x|agg10|pad] x [Wr0|Wl0|pad])
  agg10_k<<<(N_NODES + 7) / 8, 256, 0, stream>>>(x, row_off, csr, agg10, N_NODES);
  pack0_k<<<(N_NODES * 64 + 255) / 256, 256, 0, stream>>>(x, agg10, X2, N_NODES);
  mfma_gemm_k<64, false, 0, false><<<GB, 512, 0, stream>>>(
      X2, W2, nullptr, nullptr, b_l0, bn_g, bn_b, bn_m, bn_v, h,
      nullptr, nullptr, nullptr);

  // layers 1..4 (dual MFMA GEMM, in-place h update)
  for (int t = 1; t < T_LAYERS; ++t) {
    aggv_k<<<(N_NODES + 3) / 4, 256, 0, stream>>>(h, row_off, csr, agg, N_NODES);
    mfma_gemm_k<HID, true, 0, false><<<GB, 512, 0, stream>>>(
        agg, WlB + (size_t)(t - 1) * HID * HID,
        h,   WrB + (size_t)(t - 1) * HID * HID,
        b_l + (size_t)(t - 1) * HID,
        bn_g + (size_t)t * HID, bn_b + (size_t)t * HID,
        bn_m + (size_t)t * HID, bn_v + (size_t)t * HID,
        h, nullptr, nullptr, nullptr);
  }

  // projection MLP: proj0 in-place on h; proj1 fused with the 384->3 output
  mfma_gemm_k<HID, false, 1, false><<<GB, 512, 0, stream>>>(
      h, Wp0B, nullptr, nullptr, bp0, pbn_g, pbn_b, pbn_m, pbn_v, h,
      nullptr, nullptr, nullptr);
  mfma_gemm_k<HID, false, 1, true><<<GB, 512, 0, stream>>>(
      h, Wp1B, nullptr, nullptr, bp1, pbn_g + HID, pbn_b + HID, pbn_m + HID, pbn_v + HID, h,
      Wp2, bp2, (float*)d_out);
}

// Round 6
// 1045.393 us; speedup vs baseline: 1.7041x; 1.0256x over previous
//
#include <hip/hip_runtime.h>
#include <hip/hip_bf16.h>

#define N_NODES 100000
#define N_EDGES 300000
#define IN_DIM 10
#define HID 384
#define OUT_DIM 3
#define T_LAYERS 5
#define BN_EPS 1e-5f

typedef __attribute__((ext_vector_type(8))) short short8;
typedef __attribute__((ext_vector_type(4))) float floatx4;

__device__ __forceinline__ float bf16f(short v) {
  return __uint_as_float(((unsigned)(unsigned short)v) << 16);
}

// async global->LDS, 16 B per lane; dst is wave-uniform base, lane l lands at
// dst + l*16 (linear). Swizzle lives on the SOURCE address (m173 pattern).
__device__ __forceinline__ void gld_lds16(const void* g, void* l) {
  __builtin_amdgcn_global_load_lds(
      (const __attribute__((address_space(1))) void*)g,
      (__attribute__((address_space(3))) void*)l, 16, 0, 0);
}

// ------------------------- CSR build -------------------------

__global__ void count_k(const int* __restrict__ dst, int* __restrict__ cnt, int E) {
  int e = blockIdx.x * blockDim.x + threadIdx.x;
  if (e < E) atomicAdd(&cnt[dst[e]], 1);
}

__global__ void scan_partial_k(const int* __restrict__ cnt, int* __restrict__ bsum, int n) {
  int t = threadIdx.x;
  int i = blockIdx.x * 1024 + t;
  int v = (i < n) ? cnt[i] : 0;
  #pragma unroll
  for (int off = 1; off < 64; off <<= 1) v += __shfl_xor(v, off);
  __shared__ int ws[16];
  if ((t & 63) == 0) ws[t >> 6] = v;
  __syncthreads();
  if (t == 0) {
    int s = 0;
    #pragma unroll
    for (int w = 0; w < 16; ++w) s += ws[w];
    bsum[blockIdx.x] = s;
  }
}

__global__ void scan_small_k(int* __restrict__ bsum, int P) {
  __shared__ int s[1024];
  int t = threadIdx.x;
  int v = (t < P) ? bsum[t] : 0;
  s[t] = v;
  __syncthreads();
  for (int off = 1; off < 1024; off <<= 1) {
    int add = (t >= off) ? s[t - off] : 0;
    __syncthreads();
    s[t] += add;
    __syncthreads();
  }
  if (t < P) bsum[t] = s[t] - v;  // exclusive block-prefix
}

__global__ void scan_final_k(const int* __restrict__ cnt, const int* __restrict__ bsum,
                             int* __restrict__ row_off, int n) {
  int t = threadIdx.x, lane = t & 63, wv = t >> 6;
  int i = blockIdx.x * 1024 + t;
  int v = (i < n) ? cnt[i] : 0;
  int x = v;
  #pragma unroll
  for (int off = 1; off < 64; off <<= 1) {
    int y = __shfl_up(x, off);
    if (lane >= off) x += y;
  }
  __shared__ int ws[16];
  if (lane == 63) ws[wv] = x;
  __syncthreads();
  if (t == 0) {
    int a = 0;
    #pragma unroll
    for (int w = 0; w < 16; ++w) { int tmp = ws[w]; ws[w] = a; a += tmp; }
  }
  __syncthreads();
  int excl = (x - v) + ws[wv] + bsum[blockIdx.x];
  if (i <= n) row_off[i] = excl;
}

__global__ void fill_k(const int* __restrict__ src, const int* __restrict__ dst,
                       const int* __restrict__ row_off, int* __restrict__ cursor,
                       int* __restrict__ csr, int E) {
  int e = blockIdx.x * blockDim.x + threadIdx.x;
  if (e < E) {
    int d = dst[e];
    int pos = atomicAdd(&cursor[d], 1);
    csr[row_off[d] + pos] = src[e];
  }
}

// ------------------------- prepack kernels -------------------------

__global__ void conv_k(const float* __restrict__ src, __hip_bfloat16* __restrict__ dst, int n) {
  int i = blockIdx.x * blockDim.x + threadIdx.x;
  if (i < n) dst[i] = __float2bfloat16(src[i]);
}

// X2[n][64] = { x[n][0..10) , agg10[n][0..10) , 0 pad }
__global__ void pack0_k(const float* __restrict__ x, const float* __restrict__ agg10,
                        __hip_bfloat16* __restrict__ X2, int n) {
  int i = blockIdx.x * blockDim.x + threadIdx.x;
  if (i < n * 64) {
    int node = i >> 6, k = i & 63;
    float v = (k < IN_DIM) ? x[node * IN_DIM + k]
              : (k < 2 * IN_DIM) ? agg10[node * IN_DIM + (k - IN_DIM)] : 0.f;
    X2[i] = __float2bfloat16(v);
  }
}

// W2[o][64] = { W_r0 (pairs x) , W_l0 (pairs agg10) , 0 pad }
__global__ void packw0_k(const float* __restrict__ Wl, const float* __restrict__ Wr,
                         __hip_bfloat16* __restrict__ W2) {
  int i = blockIdx.x * blockDim.x + threadIdx.x;
  if (i < HID * 64) {
    int o = i >> 6, k = i & 63;
    float v = (k < IN_DIM) ? Wr[o * IN_DIM + k]
              : (k < 2 * IN_DIM) ? Wl[o * IN_DIM + (k - IN_DIM)]
              : 0.f;
    W2[i] = __float2bfloat16(v);
  }
}

// ------------------------- aggregation -------------------------

__global__ void agg10_k(const float* __restrict__ x, const int* __restrict__ row_off,
                        const int* __restrict__ csr, float* __restrict__ agg10, int n) {
  int sub = threadIdx.x >> 5;
  int lane = threadIdx.x & 31;
  int node = blockIdx.x * 8 + sub;
  if (node >= n) return;
  int s = row_off[node], e = row_off[node + 1];
  if (lane < IN_DIM) {
    float acc = 0.f;
    for (int j = s; j < e; ++j) acc += x[csr[j] * IN_DIM + lane];
    float c = (float)max(e - s, 1);
    agg10[node * IN_DIM + lane] = acc / c;
  }
}

// F=384 mean aggregation: one wave per node, lanes 0..47 hold 8 bf16 cols each.
__global__ __launch_bounds__(256) void aggv_k(const __hip_bfloat16* __restrict__ h,
                                              const int* __restrict__ row_off,
                                              const int* __restrict__ csr,
                                              __hip_bfloat16* __restrict__ agg, int n) {
  int node = blockIdx.x * 4 + (threadIdx.x >> 6);
  if (node >= n) return;
  int lane = threadIdx.x & 63;
  if (lane >= 48) return;
  int s = row_off[node], e = row_off[node + 1];
  float acc[8] = {0.f, 0.f, 0.f, 0.f, 0.f, 0.f, 0.f, 0.f};
  for (int j = s; j < e; ++j) {
    const uint4 v = *(const uint4*)(h + (size_t)csr[j] * HID + lane * 8);
    uint u0 = v.x, u1 = v.y, u2 = v.z, u3 = v.w;
    acc[0] += __uint_as_float(u0 << 16);
    acc[1] += __uint_as_float(u0 & 0xffff0000u);
    acc[2] += __uint_as_float(u1 << 16);
    acc[3] += __uint_as_float(u1 & 0xffff0000u);
    acc[4] += __uint_as_float(u2 << 16);
    acc[5] += __uint_as_float(u2 & 0xffff0000u);
    acc[6] += __uint_as_float(u3 << 16);
    acc[7] += __uint_as_float(u3 & 0xffff0000u);
  }
  float invc = 1.f / (float)max(e - s, 1);
  uint out[4];
  #pragma unroll
  for (int q = 0; q < 4; ++q) {
    __hip_bfloat16 lo = __float2bfloat16(acc[2 * q] * invc);
    __hip_bfloat16 hi = __float2bfloat16(acc[2 * q + 1] * invc);
    out[q] = (uint)(*(unsigned short*)&lo) | ((uint)(*(unsigned short*)&hi) << 16);
  }
  *(uint4*)(agg + (size_t)node * HID + lane * 8) = make_uint4(out[0], out[1], out[2], out[3]);
}

// ------------------------- MFMA GEMM, fused epilogue -------------------------
// out[i, col] = sum_k A1[i,k]*B1[col,k] (+ A2[i,k]*B2[col,k]) + bias[col]
// r12 = r11 (512 thr, gld_lds staging, 16 waves/CU) + chunk-ahead A prefetch
// with COUNTED vmcnt (T3/T4 minimum form, done right this time):
//  * r11 post-mortem: memory-bound op (ideal ~37us) running at 1.59 TB/s
//    (25% of achievable) because every chunk's loads issue after the previous
//    barrier and fully drain before compute — bursty HBM, dead time during
//    compute. Residual ~48 B/thread one-time spill (WRITE 112.5 vs 75 MB)
//    costs only ~5-9us — secondary.
//  * LDS: A double-buffer (2 x 8KB) + B single (48KB) = exactly 64 KB;
//    2 blocks/CU kept. Per chunk: stage B(c) [6 gld] -> stage A(c+1) into
//    other parity [1 gld] -> s_waitcnt vmcnt(1) (A(c+1) STAYS IN FLIGHT:
//    the HBM-cold A stream is prefetched a full chunk ahead) -> s_barrier ->
//    compute(c) -> s_barrier. B stays distance-0 but is L2-resident
//    (~200cy exposed, vs A's ~900cy now hidden).
//  * Raw s_barrier (NOT __syncthreads — that drains vmcnt(0) and would kill
//    the prefetch). vmcnt is per-wave; each wave issues 6 B + 1 A per chunk.
//  * Spill trims: inner loop holds af[4] + ONE bf live (was af[4]+bf[3]);
//    epilogue inv computed per-rt (4 live, was 16).
// Epilogue: pack bf16 to LDS (stride 392), coalesced dwordx4 out.
// In-place safe (out == A1 or A2): block reads only its own 64 rows, and the
// epilogue __syncthreads precedes all global writes.
template <int KTOT, bool DUAL, int EPI, bool FINAL>
__global__ __launch_bounds__(512, 4) void mfma_gemm_k(
    const __hip_bfloat16* __restrict__ A1, const __hip_bfloat16* __restrict__ B1,
    const __hip_bfloat16* __restrict__ A2, const __hip_bfloat16* __restrict__ B2,
    const float* __restrict__ bias,
    const float* __restrict__ bng, const float* __restrict__ bnb,
    const float* __restrict__ bnm, const float* __restrict__ bnv,
    __hip_bfloat16* __restrict__ out,
    const float* __restrict__ W3, const float* __restrict__ b3,
    float* __restrict__ out3) {
  // [0..4096)   : sA parity 0   (64 rows x 64 k)
  // [4096..8192): sA parity 1
  // [8192..32768): sB (384 cols x 64 k)
  // epilogue reuses [0..25088) as sO[64][392] and [0..512) floats as red
  __shared__ alignas(16) short smem[32768];  // 65536 B exactly
  short* sB = smem + 8192;

  const int t = threadIdx.x;
  const int lane = t & 63;
  const int wv = t >> 6;        // 0..7
  const int n16 = lane & 15;
  const int quad = lane >> 4;
  const int row0 = blockIdx.x * 64;

  // ---- staging geometry (per-thread constant source offsets) ----
  // A: one gld_lds per wave covers rows wv*8..wv*8+7; LDS short idx =
  //    bufbase + wv*512 + lane*8 -> row = wv*8 + (lane>>3), slot = lane&7;
  //    source granule g = slot ^ (row&7) (inverse of the read swizzle).
  const int aRow = t >> 3;                  // 0..63
  const int aG = (t & 7) ^ (aRow & 7);
  const int aOff = min(row0 + aRow, N_NODES - 1) * KTOT + aG * 8;  // elements
  // B: 6 gld_lds per wave, instruction j = wv*6+it covers cols j*8..j*8+7.
  int bOff[6];
  #pragma unroll
  for (int it = 0; it < 6; ++it) {
    int col = (wv * 6 + it) * 8 + (lane >> 3);
    int g = (lane & 7) ^ (col & 7);
    bOff[it] = col * KTOT + g * 8;  // elements
  }

  floatx4 acc[4][3];
  #pragma unroll
  for (int rt = 0; rt < 4; ++rt)
    #pragma unroll
    for (int ct = 0; ct < 3; ++ct) acc[rt][ct] = (floatx4)0.f;

  constexpr int KCH = KTOT / 64;
  constexpr int NCH = DUAL ? 2 * KCH : KCH;

  // prologue: prefetch A(0) into parity 0 (chunk 0 is always A1, kc=0)
  gld_lds16(A1 + aOff, smem + wv * 512);

  for (int c = 0; c < NCH; ++c) {
    const __hip_bfloat16* Bp;
    int kc;
    if (!DUAL || c < KCH) { Bp = B1; kc = c * 64; }
    else                  { Bp = B2; kc = (c - KCH) * 64; }

    // stage B(c): 6 gld_lds per wave (48 KB total)
    #pragma unroll
    for (int it = 0; it < 6; ++it)
      gld_lds16(Bp + bOff[it] + kc, sB + (wv * 6 + it) * 512);

    // prefetch A(c+1) into the other parity (stays in flight across barrier)
    if (c + 1 < NCH) {
      const __hip_bfloat16* Ap;
      int kn;
      int cn = c + 1;
      if (!DUAL || cn < KCH) { Ap = A1; kn = cn * 64; }
      else                   { Ap = A2; kn = (cn - KCH) * 64; }
      gld_lds16(Ap + aOff + kn, smem + (cn & 1) * 4096 + wv * 512);
      asm volatile("s_waitcnt vmcnt(1)" ::: "memory");  // A(c)+B(c) done
    } else {
      asm volatile("s_waitcnt vmcnt(0)" ::: "memory");  // drain everything
    }
    __builtin_amdgcn_sched_barrier(0);
    __builtin_amdgcn_s_barrier();   // staged data visible to all waves

    // compute chunk c from parity c&1
    const short* sAc = smem + (c & 1) * 4096;
    #pragma unroll
    for (int kh = 0; kh < 2; ++kh) {
      short8 af[4];
      int g = kh * 4 + quad;
      #pragma unroll
      for (int rt = 0; rt < 4; ++rt) {
        int r = rt * 16 + n16;
        af[rt] = *(const short8*)&sAc[r * 64 + ((g ^ (r & 7)) * 8)];
      }
      #pragma unroll
      for (int ct = 0; ct < 3; ++ct) {
        int cl = wv * 48 + ct * 16 + n16;
        short8 bf = *(const short8*)&sB[cl * 64 + ((g ^ (cl & 7)) * 8)];
        #pragma unroll
        for (int rt = 0; rt < 4; ++rt)
          acc[rt][ct] = __builtin_amdgcn_mfma_f32_16x16x32_bf16(af[rt], bf, acc[rt][ct], 0, 0, 0);
      }
    }
    __builtin_amdgcn_s_barrier();   // all reads of sB/sA done before re-stage
    asm volatile("" ::: "memory");
  }

  // ---- epilogue ----
  int gc[3];
  #pragma unroll
  for (int ct = 0; ct < 3; ++ct) {
    gc[ct] = wv * 48 + ct * 16 + n16;
    float bs = bias[gc[ct]];
    #pragma unroll
    for (int rt = 0; rt < 4; ++rt)
      #pragma unroll
      for (int rg = 0; rg < 4; ++rg) acc[rt][ct][rg] += bs;
  }

  if constexpr (EPI == 0) {
    // row L2 norm: 16-lane shfl partials, cross-wave (8 waves) via LDS
    float* red = (float*)smem;  // 512 floats
    #pragma unroll
    for (int rt = 0; rt < 4; ++rt)
      #pragma unroll
      for (int rg = 0; rg < 4; ++rg) {
        float s = 0.f;
        #pragma unroll
        for (int ct = 0; ct < 3; ++ct) s += acc[rt][ct][rg] * acc[rt][ct][rg];
        #pragma unroll
        for (int off = 1; off < 16; off <<= 1) s += __shfl_xor(s, off);
        if (n16 == 0) red[wv * 64 + rt * 16 + quad * 4 + rg] = s;
      }
    __syncthreads();
    #pragma unroll
    for (int rt = 0; rt < 4; ++rt) {
      float inv[4];
      #pragma unroll
      for (int rg = 0; rg < 4; ++rg) {
        int rl = rt * 16 + quad * 4 + rg;
        float ss = 0.f;
        #pragma unroll
        for (int w = 0; w < 8; ++w) ss += red[w * 64 + rl];
        inv[rg] = 1.f / fmaxf(sqrtf(ss), 1e-12f);
      }
      #pragma unroll
      for (int ct = 0; ct < 3; ++ct)
        #pragma unroll
        for (int rg = 0; rg < 4; ++rg) acc[rt][ct][rg] *= inv[rg];
    }
    __syncthreads();  // red reads done before smem reused as sO
  }

  // BN + activation, pack bf16 into LDS (row stride 392 shorts)
  constexpr int OS = 392;  // 64 * 392 * 2 B = 50176 B
  short* sO = smem;
  #pragma unroll
  for (int ct = 0; ct < 3; ++ct) {
    int col = gc[ct];
    float sc = bng[col] * rsqrtf(bnv[col] + BN_EPS);
    float sh = bnb[col] - bnm[col] * sc;
    #pragma unroll
    for (int rt = 0; rt < 4; ++rt)
      #pragma unroll
      for (int rg = 0; rg < 4; ++rg) {
        float xv = acc[rt][ct][rg] * sc + sh;
        if constexpr (EPI == 0)
          xv = xv > 0.f ? xv : expm1f(xv);
        else
          xv = fmaxf(xv, 0.f);
        __hip_bfloat16 bv = __float2bfloat16(xv);
        sO[(rt * 16 + quad * 4 + rg) * OS + col] = *(short*)&bv;
      }
  }
  __syncthreads();

  if constexpr (FINAL) {
    // fused 384 -> 3 projection from LDS; thread (row = t&63, o = t>>6), t<192
    if (t < 192) {
      int row = t & 63, o = t >> 6;
      int grow = row0 + row;
      if (grow < N_NODES) {
        float s = 0.f;
        #pragma unroll
        for (int kb = 0; kb < 48; ++kb) {
          short8 hv = *(const short8*)&sO[row * OS + kb * 8];
          #pragma unroll
          for (int j = 0; j < 8; ++j) s += bf16f(hv[j]) * W3[o * HID + kb * 8 + j];
        }
        out3[grow * OUT_DIM + o] = s + b3[o];
      }
    }
  } else {
    // 64 rows x 768 B out; 48 16B-chunks per row; 512 thr x 6 chunks
    #pragma unroll
    for (int it = 0; it < 6; ++it) {
      int e = t + it * 512;
      int row = e / 48, cs = e % 48;
      int grow = row0 + row;
      if (grow < N_NODES) {
        uint4 v = *(const uint4*)&sO[row * OS + cs * 8];
        *(uint4*)(out + (size_t)grow * HID + cs * 8) = v;
      }
    }
  }
}

// ------------------------- launcher -------------------------

extern "C" void kernel_launch(void* const* d_in, const int* in_sizes, int n_in,
                              void* d_out, int out_size, void* d_ws, size_t ws_size,
                              hipStream_t stream) {
  const float* x = (const float*)d_in[0];
  const int* ei = (const int*)d_in[1];
  const int* src = ei;
  const int* dst = ei + N_EDGES;
  const float* W_l0 = (const float*)d_in[2];
  const float* b_l0 = (const float*)d_in[3];
  const float* W_r0 = (const float*)d_in[4];
  const float* W_l = (const float*)d_in[5];
  const float* b_l = (const float*)d_in[6];
  const float* W_r = (const float*)d_in[7];
  const float* bn_g = (const float*)d_in[8];
  const float* bn_b = (const float*)d_in[9];
  const float* bn_m = (const float*)d_in[10];
  const float* bn_v = (const float*)d_in[11];
  const float* Wp0 = (const float*)d_in[12];
  const float* bp0 = (const float*)d_in[13];
  const float* Wp1 = (const float*)d_in[14];
  const float* bp1 = (const float*)d_in[15];
  const float* Wp2 = (const float*)d_in[16];
  const float* bp2 = (const float*)d_in[17];
  const float* pbn_g = (const float*)d_in[18];
  const float* pbn_b = (const float*)d_in[19];
  const float* pbn_m = (const float*)d_in[20];
  const float* pbn_v = (const float*)d_in[21];

  char* ws = (char*)d_ws;
  size_t off = 0;
  auto walloc = [&](size_t bytes) -> void* {
    void* p = ws + off;
    off = (off + bytes + 255) & ~(size_t)255;
    return p;
  };
  __hip_bfloat16* h   = (__hip_bfloat16*)walloc((size_t)N_NODES * HID * 2);  // 76.8 MB
  __hip_bfloat16* agg = (__hip_bfloat16*)walloc((size_t)N_NODES * HID * 2);  // 76.8 MB
  float* agg10 = (float*)agg;  // 4 MB fp32 overlay; agg not used until layer 1
  __hip_bfloat16* X2  = (__hip_bfloat16*)walloc((size_t)N_NODES * 64 * 2);   // 12.8 MB
  __hip_bfloat16* W2  = (__hip_bfloat16*)walloc((size_t)HID * 64 * 2);
  __hip_bfloat16* WlB  = (__hip_bfloat16*)walloc((size_t)(T_LAYERS - 1) * HID * HID * 2);
  __hip_bfloat16* WrB  = (__hip_bfloat16*)walloc((size_t)(T_LAYERS - 1) * HID * HID * 2);
  __hip_bfloat16* Wp0B = (__hip_bfloat16*)walloc((size_t)HID * HID * 2);
  __hip_bfloat16* Wp1B = (__hip_bfloat16*)walloc((size_t)HID * HID * 2);
  int* cnt     = (int*)walloc((size_t)N_NODES * 4);
  int* row_off = (int*)walloc((size_t)(N_NODES + 1) * 4);
  int* cursor  = (int*)walloc((size_t)N_NODES * 4);
  int* csr     = (int*)walloc((size_t)N_EDGES * 4);
  int* bsum    = (int*)walloc(4096);

  hipMemsetAsync(cnt, 0, (size_t)N_NODES * 4, stream);
  hipMemsetAsync(cursor, 0, (size_t)N_NODES * 4, stream);

  // weight prepack
  const int NW = (T_LAYERS - 1) * HID * HID;
  conv_k<<<(NW + 255) / 256, 256, 0, stream>>>(W_l, WlB, NW);
  conv_k<<<(NW + 255) / 256, 256, 0, stream>>>(W_r, WrB, NW);
  conv_k<<<(HID * HID + 255) / 256, 256, 0, stream>>>(Wp0, Wp0B, HID * HID);
  conv_k<<<(HID * HID + 255) / 256, 256, 0, stream>>>(Wp1, Wp1B, HID * HID);
  packw0_k<<<(HID * 64 + 255) / 256, 256, 0, stream>>>(W_l0, W_r0, W2);

  // CSR build
  count_k<<<(N_EDGES + 255) / 256, 256, 0, stream>>>(dst, cnt, N_EDGES);
  int P = (N_NODES + 1 + 1023) / 1024;
  scan_partial_k<<<P, 1024, 0, stream>>>(cnt, bsum, N_NODES);
  scan_small_k<<<1, 1024, 0, stream>>>(bsum, P);
  scan_final_k<<<P, 1024, 0, stream>>>(cnt, bsum, row_off, N_NODES);
  fill_k<<<(N_EDGES + 255) / 256, 256, 0, stream>>>(src, dst, row_off, cursor, csr, N_EDGES);

  const int GB = (N_NODES + 63) / 64;  // 1563 row-blocks

  // layer 0: agg10 -> pack -> MFMA GEMM (K=64: [x|agg10|pad] x [Wr0|Wl0|pad])
  agg10_k<<<(N_NODES + 7) / 8, 256, 0, stream>>>(x, row_off, csr, agg10, N_NODES);
  pack0_k<<<(N_NODES * 64 + 255) / 256, 256, 0, stream>>>(x, agg10, X2, N_NODES);
  mfma_gemm_k<64, false, 0, false><<<GB, 512, 0, stream>>>(
      X2, W2, nullptr, nullptr, b_l0, bn_g, bn_b, bn_m, bn_v, h,
      nullptr, nullptr, nullptr);

  // layers 1..4 (dual MFMA GEMM, in-place h update)
  for (int t = 1; t < T_LAYERS; ++t) {
    aggv_k<<<(N_NODES + 3) / 4, 256, 0, stream>>>(h, row_off, csr, agg, N_NODES);
    mfma_gemm_k<HID, true, 0, false><<<GB, 512, 0, stream>>>(
        agg, WlB + (size_t)(t - 1) * HID * HID,
        h,   WrB + (size_t)(t - 1) * HID * HID,
        b_l + (size_t)(t - 1) * HID,
        bn_g + (size_t)t * HID, bn_b + (size_t)t * HID,
        bn_m + (size_t)t * HID, bn_v + (size_t)t * HID,
        h, nullptr, nullptr, nullptr);
  }

  // projection MLP: proj0 in-place on h; proj1 fused with the 384->3 output
  mfma_gemm_k<HID, false, 1, false><<<GB, 512, 0, stream>>>(
      h, Wp0B, nullptr, nullptr, bp0, pbn_g, pbn_b, pbn_m, pbn_v, h,
      nullptr, nullptr, nullptr);
  mfma_gemm_k<HID, false, 1, true><<<GB, 512, 0, stream>>>(
      h, Wp1B, nullptr, nullptr, bp1, pbn_g + HID, pbn_b + HID, pbn_m + HID, pbn_v + HID, h,
      Wp2, bp2, (float*)d_out);
}